// Round 1
// baseline (1366.983 us; speedup 1.0000x reference)
//
#include <hip/hip_runtime.h>

// Problem constants (static per reference):
//   protein_embeds: [N=2048, L=512, D=256] float32  (1.07 GB, streamed once)
//   batch_keys:     [N=2048] sorted int32 in [0, 256), every segment non-empty
//   out:            [B=256, D=256] float32 = segment mean over all tokens
//
// Structure: two-phase, atomic-free.
//   Phase 1 (part_sum_kernel): 4096 blocks x 256 threads. Each block sums 256
//     contiguous rows of one protein-half; each thread keeps a private float4
//     partial and writes it straight to ws[16384][256] (16 MB). No LDS, no
//     barrier, no atomics, no output pre-zeroing.
//   Phase 2 (seg_mean_kernel): 256 blocks (one per segment). Binary-search the
//     protein range on the sorted keys, sum the 8*cnt partial rows from ws
//     (coalesced across threads, L2-resident), divide, store out directly.
#define N_PROT 2048
#define L_SEQ  512
#define D_DIM  256
#define B_SEG  256
#define SPLIT  2                       // blocks per protein along L
#define ROWS_PER_BLK (L_SEQ / SPLIT)   // 256
#define RG 4                           // row-groups per block (tid >> 6)
#define PARTS_PER_PROT (SPLIT * RG)    // 8 partial rows per protein in ws
// ws footprint: N_PROT*SPLIT*RG rows x 256 floats = 16384*1KB = 16 MB (<< ws_size)

__global__ __launch_bounds__(256) void part_sum_kernel(const float* __restrict__ x,
                                                       float* __restrict__ ws) {
    const int blk = blockIdx.x;          // 0..4095, contiguous 256 KiB chunk each
    const int tid = threadIdx.x;
    const int dq  = tid & 63;            // float4 lane across D=256
    const int r   = tid >> 6;            // row group 0..3

    const float4* base = (const float4*)x + (size_t)blk * ROWS_PER_BLK * (D_DIM / 4);

    // Two independent accumulators -> 2 loads per iteration with no add-chain
    // dependency between them; unroll 4 keeps ~8 loads in flight per thread.
    float4 a0 = make_float4(0.f, 0.f, 0.f, 0.f);
    float4 a1 = make_float4(0.f, 0.f, 0.f, 0.f);
    #pragma unroll 4
    for (int l = r; l < ROWS_PER_BLK; l += 2 * RG) {
        float4 v0 = base[(size_t)l * (D_DIM / 4) + dq];
        float4 v1 = base[(size_t)(l + RG) * (D_DIM / 4) + dq];
        a0.x += v0.x; a0.y += v0.y; a0.z += v0.z; a0.w += v0.w;
        a1.x += v1.x; a1.y += v1.y; a1.z += v1.z; a1.w += v1.w;
    }
    float4 s = make_float4(a0.x + a1.x, a0.y + a1.y, a0.z + a1.z, a0.w + a1.w);

    // Private partial -> ws row (blk*RG + r); no reduction, no atomics.
    float4* wsr = (float4*)ws + (size_t)(blk * RG + r) * (D_DIM / 4);
    wsr[dq] = s;
}

// One block per segment, one thread per d. Sum the 8*cnt partial rows.
__global__ __launch_bounds__(256) void seg_mean_kernel(const float* __restrict__ ws,
                                                       const int* __restrict__ keys,
                                                       float* __restrict__ out) {
    const int b = blockIdx.x;
    const int d = threadIdx.x;

    // lower_bound(b) over sorted keys
    int lo = 0, hi = N_PROT;
    while (lo < hi) { int mid = (lo + hi) >> 1; if (keys[mid] <  b) lo = mid + 1; else hi = mid; }
    const int start = lo;
    // upper_bound(b)
    hi = N_PROT;
    while (lo < hi) { int mid = (lo + hi) >> 1; if (keys[mid] <= b) lo = mid + 1; else hi = mid; }
    const int end = lo;

    const int row0 = start * PARTS_PER_PROT;
    const int row1 = end   * PARTS_PER_PROT;

    float s = 0.f;
    for (int rr = row0; rr < row1; ++rr)         // avg 64 coalesced reads, L2-hot
        s += ws[(size_t)rr * D_DIM + d];

    const float cnt_tokens = (float)((end - start) * L_SEQ);
    out[(size_t)b * D_DIM + d] = s / cnt_tokens;
}

extern "C" void kernel_launch(void* const* d_in, const int* in_sizes, int n_in,
                              void* d_out, int out_size, void* d_ws, size_t ws_size,
                              hipStream_t stream) {
    const float* x    = (const float*)d_in[0];
    const int*   keys = (const int*)d_in[1];
    float* out        = (float*)d_out;
    float* ws         = (float*)d_ws;

    // No hipMemsetAsync needed: out is fully overwritten by seg_mean_kernel
    // (every segment is non-empty per the reference), and ws rows are fully
    // overwritten by part_sum_kernel before being read.
    part_sum_kernel<<<N_PROT * SPLIT, 256, 0, stream>>>(x, ws);
    seg_mean_kernel<<<B_SEG, 256, 0, stream>>>(ws, keys, out);
}